// Round 13
// baseline (109.986 us; speedup 1.0000x reference)
//
#include <hip/hip_runtime.h>
#include <cstdint>
#include <cstddef>

#define DEVINL __device__ __forceinline__

constexpr int S_ = 2048;
constexpr int D_ = 512;
constexpr int H_ = 8;
constexpr float SCALE_ = 0.125f;                 // 1/sqrt(64)
constexpr float SCALE_L2E_ = 0.18033688011112f;  // SCALE * log2(e), for exp2-domain scores

using short8 = __attribute__((ext_vector_type(8))) short;
using f32x4  = __attribute__((ext_vector_type(4))) float;

DEVINL unsigned short f2bf(float f){
  unsigned u = __builtin_bit_cast(unsigned, f);
  u += 0x7FFFu + ((u >> 16) & 1u);          // round-to-nearest-even
  return (unsigned short)(u >> 16);
}
DEVINL float bf2f(unsigned short h){
  return __builtin_bit_cast(float, ((unsigned)h) << 16);
}

// Raw v_exp_f32 via the intrinsic (NOT inline asm: the TRANS-op result
// hazard needs compiler-inserted wait states; asm blobs are opaque to the
// hazard recognizer and produced NaNs in R5).
DEVINL float fast_exp2(float x){ return __builtin_amdgcn_exp2f(x); }

DEVINL void gload16(const void* g, void* l){
  __builtin_amdgcn_global_load_lds(
      (__attribute__((address_space(1))) void*)(g),
      (__attribute__((address_space(3))) void*)(l), 16, 0, 0);
}

// ---------------- cast x (f32 -> bf16), 8 elems/thread ----------------
__global__ void cast_x_kernel(const float* __restrict__ x, unsigned short* __restrict__ xb){
  int i = blockIdx.x * 256 + threadIdx.x;
  const float* p = x + (size_t)i * 8;
  float4 a = *(const float4*)p;
  float4 b = *(const float4*)(p + 4);
  short8 o;
  o[0]=f2bf(a.x); o[1]=f2bf(a.y); o[2]=f2bf(a.z); o[3]=f2bf(a.w);
  o[4]=f2bf(b.x); o[5]=f2bf(b.y); o[6]=f2bf(b.z); o[7]=f2bf(b.w);
  *(short8*)(xb + (size_t)i*8) = o;
}

// ---------------- mask (67MB int32) -> bit array (2MB) ----------------
__global__ void mask_bits_kernel(const int* __restrict__ mask, unsigned char* __restrict__ bits){
  unsigned tid = blockIdx.x * 256 + threadIdx.x;   // 2048 blocks -> 524288 threads
  #pragma unroll
  for (int it = 0; it < 4; ++it){
    size_t bidx = (size_t)tid + (size_t)it * 524288;
    const int* p = mask + bidx * 8;
    int4 a = *(const int4*)p;
    int4 c = *(const int4*)(p + 4);
    unsigned v = (unsigned)(a.x != 0)       | ((unsigned)(a.y != 0) << 1)
               | ((unsigned)(a.z != 0) << 2) | ((unsigned)(a.w != 0) << 3)
               | ((unsigned)(c.x != 0) << 4) | ((unsigned)(c.y != 0) << 5)
               | ((unsigned)(c.z != 0) << 6) | ((unsigned)(c.w != 0) << 7);
    bits[bidx] = (unsigned char)v;
  }
}

// ---------------- transpose+cast W [K][N] f32 -> WT [N][K] bf16 -------
// z selects which W (Wq/Wk/Wv/Wo); Wq gets SCALE*log2e folded in.
__global__ void castT_kernel(const float* __restrict__ W0, const float* __restrict__ W1,
                             const float* __restrict__ W2, const float* __restrict__ W3,
                             unsigned short* __restrict__ WT){
  __shared__ float tile[32][33];
  const int z = blockIdx.z;
  const float* W = (z==0) ? W0 : (z==1 ? W1 : (z==2 ? W2 : W3));
  const float scale = (z==0) ? SCALE_L2E_ : 1.0f;
  unsigned short* out = WT + (size_t)z * D_ * D_;
  int n0 = blockIdx.x*32, k0 = blockIdx.y*32;
  int tx = threadIdx.x, ty = threadIdx.y;       // block (32,8)
  #pragma unroll
  for (int j=0;j<4;j++)
    tile[ty+j*8][tx] = W[(size_t)(k0+ty+j*8)*D_ + n0+tx];
  __syncthreads();
  #pragma unroll
  for (int j=0;j<4;j++)
    out[(size_t)(n0+ty+j*8)*D_ + k0+tx] = f2bf(tile[tx][ty+j*8]*scale);
}

// ---------------- GEMM: C[z] = A[z][M,512] @ BT[z][512,512]^T + bias --
// 128x128 tile, BK=64, 4 waves (2x2), mfma 16x16x32 bf16.
// LDS XOR-swizzled via pre-swizzled global_load_lds source (rule #21).
template<typename OutT>
__global__ __launch_bounds__(256) void gemm_bt(
    const unsigned short* __restrict__ A, long long Az,
    const unsigned short* __restrict__ BT, long long Bz,
    const float* __restrict__ bias0, const float* __restrict__ bias1, const float* __restrict__ bias2,
    float bs0, float bs1, float bs2,
    OutT* __restrict__ Cp, long long Cz)
{
  __shared__ unsigned short As[128*64];
  __shared__ unsigned short Bs[128*64];
  const int z = blockIdx.z;
  const unsigned short* Ab = A + (size_t)z*Az;
  const unsigned short* Bb = BT + (size_t)z*Bz;
  const float* bias = (z==0) ? bias0 : (z==1 ? bias1 : bias2);
  const float bscale = (z==0) ? bs0 : (z==1 ? bs1 : bs2);
  OutT* C = Cp + (size_t)z*Cz;
  const int m0 = blockIdx.y*128, n0 = blockIdx.x*128;
  const int t = threadIdx.x, lane = t & 63, w = t >> 6;
  const int wr = w >> 1, wc = w & 1;
  const int g = lane >> 4, lq = lane & 15;
  f32x4 acc[4][4] = {};
  for (int kk = 0; kk < D_; kk += 64){
    #pragma unroll
    for (int p = 0; p < 4; p++){
      int o = p*4096 + t*16;
      int row = o >> 7;                 // LDS row (0..127), 128B/row
      int cb  = o & 127;
      int scb = cb ^ ((row & 7) << 4);  // pre-swizzle the SOURCE
      gload16((const char*)Ab + ((size_t)(m0+row)*D_ + kk)*2 + scb, (char*)As + o);
      gload16((const char*)Bb + ((size_t)(n0+row)*D_ + kk)*2 + scb, (char*)Bs + o);
    }
    __syncthreads();
    #pragma unroll
    for (int ks = 0; ks < 2; ks++){
      short8 af[4], bf[4];
      #pragma unroll
      for (int i = 0; i < 4; i++){
        int rowA = wr*64 + i*16 + lq;
        af[i] = *(const short8*)((const char*)As + ((rowA*128 + ks*64 + g*16) ^ ((rowA&7)<<4)));
        int rowB = wc*64 + i*16 + lq;
        bf[i] = *(const short8*)((const char*)Bs + ((rowB*128 + ks*64 + g*16) ^ ((rowB&7)<<4)));
      }
      #pragma unroll
      for (int i = 0; i < 4; i++)
        #pragma unroll
        for (int j = 0; j < 4; j++)
          acc[i][j] = __builtin_amdgcn_mfma_f32_16x16x32_bf16(af[i], bf[j], acc[i][j], 0, 0, 0);
    }
    __syncthreads();
  }
  #pragma unroll
  for (int i = 0; i < 4; i++){
    #pragma unroll
    for (int j = 0; j < 4; j++){
      int col = n0 + wc*64 + j*16 + lq;
      float bvv = bias[col]*bscale;
      #pragma unroll
      for (int r = 0; r < 4; r++){
        int row = m0 + wr*64 + i*16 + g*4 + r;   // C/D: col=lane&15, row=4g+reg (m89)
        float v = acc[i][j][r] + bvv;
        if constexpr (sizeof(OutT) == 4) C[(size_t)row*D_ + col] = (OutT)v;
        else                             C[(size_t)row*D_ + col] = (OutT)f2bf(v);
      }
    }
  }
}

// ---------------- attention partial Z/M per q-row ---------------------
// 1024 1-D blocks of 512 threads; decode kz = bid&7 so the 4 qt-blocks
// sharing one K-tile land on the SAME XCD (round-robin dispatch) -> one
// L2 fill per K-tile instead of four. Wave w owns q-rows qt*512+w*64.
// Partials go to private [kz] slots with plain stores (no memset, no
// atomics; every slot written exactly once). Body = proven R12 codegen.
__global__ __launch_bounds__(512) void attn_zm_kernel(
    const unsigned short* __restrict__ Q, const unsigned short* __restrict__ Kg,
    const unsigned* __restrict__ bitsW, float* __restrict__ Zp, float* __restrict__ Mp)
{
  __shared__ unsigned short Ks[256*64];   // 32KB, swizzled rows of 128B
  const int bid = blockIdx.x;
  const int kz = bid & 7;
  const int qt = (bid >> 3) & 3;
  const int bh = bid >> 5;                // 0..31
  const int b = bh >> 3, h = bh & 7;
  const int t = threadIdx.x, lane = t & 63, w = t >> 6;
  const int g = lane >> 4, lq = lane & 15;
  const int qbase = qt*512 + w*64;

  // stage K-tile: 4 x gload16 per thread (512 threads), pre-swizzled src
  const char* Kgb = (const char*)Kg + ((size_t)(b*S_ + kz*256))*1024 + h*128;
  #pragma unroll
  for (int p = 0; p < 4; p++){
    int o = p*8192 + t*16;
    int row = o >> 7;                   // 128B per k-row
    int scb = (o & 127) ^ ((row & 7) << 4);
    gload16(Kgb + (size_t)row*1024 + scb, (char*)Ks + o);
  }

  // mask-bit words: 4 q-rows x 8 k-tiles, preloaded (static idx)
  unsigned wb[4][8];
  #pragma unroll
  for (int qs = 0; qs < 4; qs++){
    const uint4* wp = (const uint4*)(bitsW + ((size_t)(b*S_ + qbase + qs*16 + lq))*(S_/32) + kz*8);
    uint4 wA = wp[0], wB = wp[1];
    wb[qs][0]=wA.x; wb[qs][1]=wA.y; wb[qs][2]=wA.z; wb[qs][3]=wA.w;
    wb[qs][4]=wB.x; wb[qs][5]=wB.y; wb[qs][6]=wB.z; wb[qs][7]=wB.w;
  }

  short8 qf[4][2];                        // Q rows in regs (pre-scaled by SCALE*log2e)
  #pragma unroll
  for (int qs = 0; qs < 4; qs++)
    #pragma unroll
    for (int c = 0; c < 2; c++)
      qf[qs][c] = *(const short8*)(Q + ((size_t)(b*S_ + qbase + qs*16 + lq))*D_ + h*64 + c*32 + g*8);

  float Z[4], Mm[4];
  #pragma unroll
  for (int qs = 0; qs < 4; qs++){ Z[qs] = 0.f; Mm[qs] = 0.f; }

  __syncthreads();                        // K-tile ready (the only barrier)

  #pragma unroll
  for (int i = 0; i < 16; ++i){           // i covers k rows i*16 .. i*16+15
    const int kt2 = i >> 1, ks = i & 1;
    const int row = i*16 + lq;
    const int sw = (row & 7) << 4;
    short8 A0 = *(const short8*)((const char*)Ks + row*128 + ((g*16) ^ sw));
    short8 A1 = *(const short8*)((const char*)Ks + row*128 + ((64 + g*16) ^ sw));
    #pragma unroll
    for (int qs = 0; qs < 4; qs++){
      f32x4 d = {0.f,0.f,0.f,0.f};
      d = __builtin_amdgcn_mfma_f32_16x16x32_bf16(A0, qf[qs][0], d, 0, 0, 0);
      d = __builtin_amdgcn_mfma_f32_16x16x32_bf16(A1, qf[qs][1], d, 0, 0, 0);
      // d[r]: score(exp2-dom) for kpos = kz*256 + i*16 + 4g + r,
      // q-row = qbase + qs*16 + lq (col=lane&15)
      unsigned nib = wb[qs][kt2] >> (ks*16 + g*4);
      #pragma unroll
      for (int r = 0; r < 4; r++){
        float p = fast_exp2(d[r]);
        Z[qs] += p;
        Mm[qs] = fmaf((float)((nib >> r) & 1u), p, Mm[qs]);
      }
    }
  }
  // merge the 4 k-subsets (lane groups) per q-row; one plain store per row
  #pragma unroll
  for (int qs = 0; qs < 4; qs++){
    Z[qs]  += __shfl_xor(Z[qs], 16);  Mm[qs] += __shfl_xor(Mm[qs], 16);
    Z[qs]  += __shfl_xor(Z[qs], 32);  Mm[qs] += __shfl_xor(Mm[qs], 32);
  }
  if (g == 0){
    size_t base = ((size_t)(kz*32 + bh))*S_ + qbase + lq;   // [kz][bh][2048]
    #pragma unroll
    for (int qs = 0; qs < 4; qs++){
      Zp[base + qs*16] = Z[qs];
      Mp[base + qs*16] = Mm[qs];
    }
  }
}

// ---------------- finalize: s[b,h] = sum_q (Z-M)/Z over kz slots ------
__global__ __launch_bounds__(256) void finalize_s(const float* __restrict__ Zp,
                                                  const float* __restrict__ Mp,
                                                  float* __restrict__ sbh){
  const int bh = blockIdx.x;            // 32 blocks
  const int t = threadIdx.x;
  float acc = 0.f;
  for (int q = t; q < S_; q += 256){
    float z = 0.f, m = 0.f;
    #pragma unroll
    for (int kz = 0; kz < 8; kz++){
      size_t idx = ((size_t)(kz*32 + bh))*S_ + q;
      z += Zp[idx];
      m += Mp[idx];
    }
    acc += (z - m) / z;
  }
  #pragma unroll
  for (int m = 1; m < 64; m <<= 1) acc += __shfl_xor(acc, m);
  __shared__ float wsum[4];
  if ((t & 63) == 0) wsum[t >> 6] = acc;
  __syncthreads();
  if (t == 0) sbh[bh] = wsum[0] + wsum[1] + wsum[2] + wsum[3];
}

// ---------------- fold s into Wo columns: WoST[b][n][k] = WoT[n][k]*s[b,k/64]
__global__ void scale_woT_kernel(const unsigned short* __restrict__ WoT,
                                 const float* __restrict__ sbh,
                                 unsigned short* __restrict__ outw){
  int i = blockIdx.x*256 + threadIdx.x;   // 131072 threads, 8 elems each
  size_t e = (size_t)i * 8;
  int k = (int)(e & 511);
  int n = (int)((e >> 9) & 511);
  int b = (int)(e >> 18);
  float sv = sbh[b*H_ + (k >> 6)];
  short8 wv = *(const short8*)(WoT + (size_t)n*D_ + k);
  short8 o;
  #pragma unroll
  for (int j = 0; j < 8; j++) o[j] = (short)f2bf(bf2f((unsigned short)wv[j]) * sv);
  *(short8*)(outw + e) = o;
}

extern "C" void kernel_launch(void* const* d_in, const int* in_sizes, int n_in,
                              void* d_out, int out_size, void* d_ws, size_t ws_size,
                              hipStream_t stream) {
  (void)in_sizes; (void)n_in; (void)out_size; (void)ws_size;
  const float* x  = (const float*)d_in[0];
  const int* mask = (const int*)d_in[1];
  const float* Wq = (const float*)d_in[2];
  const float* bq = (const float*)d_in[3];
  const float* Wk = (const float*)d_in[4];
  const float* bk = (const float*)d_in[5];
  const float* Wv = (const float*)d_in[6];
  const float* bv = (const float*)d_in[7];
  const float* Wo = (const float*)d_in[8];
  const float* bo = (const float*)d_in[9];
  float* out = (float*)d_out;

  char* ws = (char*)d_ws;
  unsigned short* xb   = (unsigned short*)(ws);             // 8 MB, dead after QKV gemm
  unsigned short* wT   = (unsigned short*)(ws +  8388608);  // WqT,WkT,WvT,WoT (4x512 KB)
  unsigned short* woT  = (unsigned short*)(ws +  9961472);  //   (= wT + 3*262144)
  unsigned short* Qb   = (unsigned short*)(ws + 10485760);
  unsigned short* Kb   = (unsigned short*)(ws + 18874368);
  unsigned short* Vb   = (unsigned short*)(ws + 27262976);
  unsigned short* woST = (unsigned short*)(ws + 35651584);  // 4x512 KB
  float*          sbh  = (float*)         (ws + 37748736);  // 32 floats
  // Z/M per-kz partials overlap the (dead-by-then) xb region: 2 x 2 MB
  float*          Zp   = (float*)(ws);
  float*          Mp   = (float*)(ws + 2097152);
  // mask bit array (2MB) overlaps woST: bits die before scale_woT writes it
  unsigned char*  bits = (unsigned char*)(ws + 35651584);

  cast_x_kernel<<<2048, 256, 0, stream>>>(x, xb);
  castT_kernel<<<dim3(16,16,4), dim3(32,8), 0, stream>>>(Wq, Wk, Wv, Wo, wT);
  mask_bits_kernel<<<2048, 256, 0, stream>>>(mask, bits);

  // QKV projections: z=0..2 -> Q,K,V (bias for Q scaled by SCALE*log2e too)
  gemm_bt<unsigned short><<<dim3(4,64,3), 256, 0, stream>>>(
      xb, 0LL, wT, 262144LL, bq, bk, bv, SCALE_L2E_, 1.0f, 1.0f, Qb, 4194304LL);

  attn_zm_kernel<<<1024, 512, 0, stream>>>(Qb, Kb, (const unsigned*)bits, Zp, Mp);
  finalize_s<<<32, 256, 0, stream>>>(Zp, Mp, sbh);

  scale_woT_kernel<<<512, 256, 0, stream>>>(woT, sbh, woST);

  // out[b] = V[b] @ WoST[b]^T + bo  (fp32 out)
  gemm_bt<float><<<dim3(4,16,4), 256, 0, stream>>>(
      Vb, 1048576LL, woST, 262144LL, bo, bo, bo, 1.0f, 1.0f, 1.0f, out, 1048576LL);
}

// Round 14
// 102.792 us; speedup vs baseline: 1.0700x; 1.0700x over previous
//
#include <hip/hip_runtime.h>
#include <cstdint>
#include <cstddef>

#define DEVINL __device__ __forceinline__

constexpr int S_ = 2048;
constexpr int D_ = 512;
constexpr int H_ = 8;
constexpr float SCALE_ = 0.125f;                 // 1/sqrt(64)
constexpr float SCALE_L2E_ = 0.18033688011112f;  // SCALE * log2(e), for exp2-domain scores

using short8 = __attribute__((ext_vector_type(8))) short;
using f32x4  = __attribute__((ext_vector_type(4))) float;

DEVINL unsigned short f2bf(float f){
  unsigned u = __builtin_bit_cast(unsigned, f);
  u += 0x7FFFu + ((u >> 16) & 1u);          // round-to-nearest-even
  return (unsigned short)(u >> 16);
}
DEVINL float bf2f(unsigned short h){
  return __builtin_bit_cast(float, ((unsigned)h) << 16);
}

// Raw v_exp_f32 via the intrinsic (NOT inline asm: the TRANS-op result
// hazard needs compiler-inserted wait states; asm blobs are opaque to the
// hazard recognizer and produced NaNs in R5).
DEVINL float fast_exp2(float x){ return __builtin_amdgcn_exp2f(x); }

DEVINL void gload16(const void* g, void* l){
  __builtin_amdgcn_global_load_lds(
      (__attribute__((address_space(1))) void*)(g),
      (__attribute__((address_space(3))) void*)(l), 16, 0, 0);
}

// ---------------- fused prep: cast_x | mask_bits | castT --------------
// bid <2048: x f32->bf16 (8 elems/thread)
// bid <4096: mask int32 -> bit array
// else     : W transpose+cast, z = (bid-4096)>>8 selects Wq/Wk/Wv/Wo
__global__ __launch_bounds__(256) void prep_kernel(
    const float* __restrict__ x, unsigned short* __restrict__ xb,
    const int* __restrict__ mask, unsigned char* __restrict__ bits,
    const float* __restrict__ W0, const float* __restrict__ W1,
    const float* __restrict__ W2, const float* __restrict__ W3,
    unsigned short* __restrict__ WT)
{
  __shared__ float tile[32][33];
  const int bid = blockIdx.x, t = threadIdx.x;
  if (bid < 2048){
    int i = bid * 256 + t;
    const float* p = x + (size_t)i * 8;
    float4 a = *(const float4*)p;
    float4 b = *(const float4*)(p + 4);
    short8 o;
    o[0]=f2bf(a.x); o[1]=f2bf(a.y); o[2]=f2bf(a.z); o[3]=f2bf(a.w);
    o[4]=f2bf(b.x); o[5]=f2bf(b.y); o[6]=f2bf(b.z); o[7]=f2bf(b.w);
    *(short8*)(xb + (size_t)i*8) = o;
  } else if (bid < 4096){
    unsigned tid = (bid - 2048) * 256 + t;
    #pragma unroll
    for (int it = 0; it < 4; ++it){
      size_t bidx = (size_t)tid + (size_t)it * 524288;
      const int* p = mask + bidx * 8;
      int4 a = *(const int4*)p;
      int4 c = *(const int4*)(p + 4);
      unsigned v = (unsigned)(a.x != 0)       | ((unsigned)(a.y != 0) << 1)
                 | ((unsigned)(a.z != 0) << 2) | ((unsigned)(a.w != 0) << 3)
                 | ((unsigned)(c.x != 0) << 4) | ((unsigned)(c.y != 0) << 5)
                 | ((unsigned)(c.z != 0) << 6) | ((unsigned)(c.w != 0) << 7);
      bits[bidx] = (unsigned char)v;
    }
  } else {
    const int b2 = bid - 4096;            // 0..1023
    const int z = b2 >> 8, r = b2 & 255;
    const float* W = (z==0) ? W0 : (z==1 ? W1 : (z==2 ? W2 : W3));
    const float scale = (z==0) ? SCALE_L2E_ : 1.0f;
    unsigned short* out = WT + (size_t)z * D_ * D_;
    const int n0 = (r & 15)*32, k0 = (r >> 4)*32;
    const int tx = t & 31, ty = t >> 5;   // 32 x 8
    #pragma unroll
    for (int j=0;j<4;j++)
      tile[ty+j*8][tx] = W[(size_t)(k0+ty+j*8)*D_ + n0+tx];
    __syncthreads();
    #pragma unroll
    for (int j=0;j<4;j++)
      out[(size_t)(n0+ty+j*8)*D_ + k0+tx] = f2bf(tile[tx][ty+j*8]*scale);
  }
}

// ---------------- GEMM: C[z] = A[z][M,512] @ BT[z][512,512]^T + bias --
// 128x128 tile, BK=64, 4 waves (2x2), mfma 16x16x32 bf16.
// LDS XOR-swizzled via pre-swizzled global_load_lds source (rule #21).
template<typename OutT>
__global__ __launch_bounds__(256) void gemm_bt(
    const unsigned short* __restrict__ A, long long Az,
    const unsigned short* __restrict__ BT, long long Bz,
    const float* __restrict__ bias0, const float* __restrict__ bias1, const float* __restrict__ bias2,
    float bs0, float bs1, float bs2,
    OutT* __restrict__ Cp, long long Cz)
{
  __shared__ unsigned short As[128*64];
  __shared__ unsigned short Bs[128*64];
  const int z = blockIdx.z;
  const unsigned short* Ab = A + (size_t)z*Az;
  const unsigned short* Bb = BT + (size_t)z*Bz;
  const float* bias = (z==0) ? bias0 : (z==1 ? bias1 : bias2);
  const float bscale = (z==0) ? bs0 : (z==1 ? bs1 : bs2);
  OutT* C = Cp + (size_t)z*Cz;
  const int m0 = blockIdx.y*128, n0 = blockIdx.x*128;
  const int t = threadIdx.x, lane = t & 63, w = t >> 6;
  const int wr = w >> 1, wc = w & 1;
  const int g = lane >> 4, lq = lane & 15;
  f32x4 acc[4][4] = {};
  for (int kk = 0; kk < D_; kk += 64){
    #pragma unroll
    for (int p = 0; p < 4; p++){
      int o = p*4096 + t*16;
      int row = o >> 7;                 // LDS row (0..127), 128B/row
      int cb  = o & 127;
      int scb = cb ^ ((row & 7) << 4);  // pre-swizzle the SOURCE
      gload16((const char*)Ab + ((size_t)(m0+row)*D_ + kk)*2 + scb, (char*)As + o);
      gload16((const char*)Bb + ((size_t)(n0+row)*D_ + kk)*2 + scb, (char*)Bs + o);
    }
    __syncthreads();
    #pragma unroll
    for (int ks = 0; ks < 2; ks++){
      short8 af[4], bf[4];
      #pragma unroll
      for (int i = 0; i < 4; i++){
        int rowA = wr*64 + i*16 + lq;
        af[i] = *(const short8*)((const char*)As + ((rowA*128 + ks*64 + g*16) ^ ((rowA&7)<<4)));
        int rowB = wc*64 + i*16 + lq;
        bf[i] = *(const short8*)((const char*)Bs + ((rowB*128 + ks*64 + g*16) ^ ((rowB&7)<<4)));
      }
      #pragma unroll
      for (int i = 0; i < 4; i++)
        #pragma unroll
        for (int j = 0; j < 4; j++)
          acc[i][j] = __builtin_amdgcn_mfma_f32_16x16x32_bf16(af[i], bf[j], acc[i][j], 0, 0, 0);
    }
    __syncthreads();
  }
  #pragma unroll
  for (int i = 0; i < 4; i++){
    #pragma unroll
    for (int j = 0; j < 4; j++){
      int col = n0 + wc*64 + j*16 + lq;
      float bvv = bias[col]*bscale;
      #pragma unroll
      for (int r = 0; r < 4; r++){
        int row = m0 + wr*64 + i*16 + g*4 + r;   // C/D: col=lane&15, row=4g+reg (m89)
        float v = acc[i][j][r] + bvv;
        if constexpr (sizeof(OutT) == 4) C[(size_t)row*D_ + col] = (OutT)v;
        else                             C[(size_t)row*D_ + col] = (OutT)f2bf(v);
      }
    }
  }
}

// ---------------- attention partial Z/M per q-row ---------------------
// 1024 1-D blocks of 512 threads (kz=bid&7 -> XCD-local K-tiles). Wave w
// owns q-rows qt*512+w*64. K-tile (256 rows) staged as TWO 16KB halves
// with counted s_waitcnt vmcnt(2) (T4): half-1's loads stay in flight
// under half-0's compute. Registers/grid/LDS identical to R12/R13 (the
// wb uint4 pair was already per-half). Inner body = proven R12 codegen.
__global__ __launch_bounds__(512) void attn_zm_kernel(
    const unsigned short* __restrict__ Q, const unsigned short* __restrict__ Kg,
    const unsigned* __restrict__ bitsW, float* __restrict__ Zp, float* __restrict__ Mp)
{
  __shared__ unsigned short Ks[2][128*64];  // 2 x 16KB, swizzled rows of 128B
  const int bid = blockIdx.x;
  const int kz = bid & 7;
  const int qt = (bid >> 3) & 3;
  const int bh = bid >> 5;                // 0..31
  const int b = bh >> 3, h = bh & 7;
  const int t = threadIdx.x, lane = t & 63, w = t >> 6;
  const int g = lane >> 4, lq = lane & 15;
  const int qbase = qt*512 + w*64;

  // qf + wb loads FIRST (pinned before the gloads so vmcnt counting of
  // the K-stage is exact; their own waits are compiler-inserted at use)
  unsigned wb[4][8];
  #pragma unroll
  for (int qs = 0; qs < 4; qs++){
    const uint4* wp = (const uint4*)(bitsW + ((size_t)(b*S_ + qbase + qs*16 + lq))*(S_/32) + kz*8);
    uint4 wA = wp[0], wB = wp[1];
    wb[qs][0]=wA.x; wb[qs][1]=wA.y; wb[qs][2]=wA.z; wb[qs][3]=wA.w;
    wb[qs][4]=wB.x; wb[qs][5]=wB.y; wb[qs][6]=wB.z; wb[qs][7]=wB.w;
  }
  short8 qf[4][2];                        // Q rows in regs (pre-scaled by SCALE*log2e)
  #pragma unroll
  for (int qs = 0; qs < 4; qs++)
    #pragma unroll
    for (int c = 0; c < 2; c++)
      qf[qs][c] = *(const short8*)(Q + ((size_t)(b*S_ + qbase + qs*16 + lq))*D_ + h*64 + c*32 + g*8);
  __builtin_amdgcn_sched_barrier(0);

  // stage half 0 (k-rows 0..127) then half 1 (128..255); 2 gload16 each
  const char* Kgb = (const char*)Kg + ((size_t)(b*S_ + kz*256))*1024 + h*128;
  #pragma unroll
  for (int p = 0; p < 2; p++){
    int o = p*8192 + t*16;
    int row = o >> 7;
    int scb = (o & 127) ^ ((row & 7) << 4);
    gload16(Kgb + (size_t)row*1024 + scb, (char*)Ks[0] + o);
  }
  #pragma unroll
  for (int p = 0; p < 2; p++){
    int o = p*8192 + t*16;
    int row = o >> 7;
    int scb = (o & 127) ^ ((row & 7) << 4);
    gload16(Kgb + (size_t)(row + 128)*1024 + scb, (char*)Ks[1] + o);
  }

  float Z[4], Mm[4];
  #pragma unroll
  for (int qs = 0; qs < 4; qs++){ Z[qs] = 0.f; Mm[qs] = 0.f; }

  // wait for OWN half-0 gloads (2 younger half-1 gloads stay in flight),
  // then barrier: collectively half-0 is staged.
  asm volatile("s_waitcnt vmcnt(2)" ::: "memory");
  __builtin_amdgcn_sched_barrier(0);
  __builtin_amdgcn_s_barrier();

#define ATTN_HALF(HB, WOFF)                                                       \
  _Pragma("unroll")                                                               \
  for (int i = 0; i < 8; ++i){                                                    \
    const int row = i*16 + lq;                                                    \
    const int sw = (row & 7) << 4;                                                \
    short8 A0 = *(const short8*)((const char*)Ks[HB] + row*128 + ((g*16) ^ sw));  \
    short8 A1 = *(const short8*)((const char*)Ks[HB] + row*128 + ((64 + g*16) ^ sw)); \
    _Pragma("unroll")                                                             \
    for (int qs = 0; qs < 4; qs++){                                               \
      f32x4 d = {0.f,0.f,0.f,0.f};                                                \
      d = __builtin_amdgcn_mfma_f32_16x16x32_bf16(A0, qf[qs][0], d, 0, 0, 0);     \
      d = __builtin_amdgcn_mfma_f32_16x16x32_bf16(A1, qf[qs][1], d, 0, 0, 0);     \
      unsigned nib = wb[qs][WOFF + (i >> 1)] >> ((i & 1)*16 + g*4);               \
      _Pragma("unroll")                                                           \
      for (int r = 0; r < 4; r++){                                                \
        float p = fast_exp2(d[r]);                                                \
        Z[qs] += p;                                                               \
        Mm[qs] = fmaf((float)((nib >> r) & 1u), p, Mm[qs]);                       \
      }                                                                           \
    }                                                                             \
  }

  ATTN_HALF(0, 0)

  // drain half-1 gloads, barrier, compute half 1
  asm volatile("s_waitcnt vmcnt(0)" ::: "memory");
  __builtin_amdgcn_sched_barrier(0);
  __builtin_amdgcn_s_barrier();

  ATTN_HALF(1, 4)
#undef ATTN_HALF

  // merge the 4 k-subsets (lane groups) per q-row; one plain store per row
  #pragma unroll
  for (int qs = 0; qs < 4; qs++){
    Z[qs]  += __shfl_xor(Z[qs], 16);  Mm[qs] += __shfl_xor(Mm[qs], 16);
    Z[qs]  += __shfl_xor(Z[qs], 32);  Mm[qs] += __shfl_xor(Mm[qs], 32);
  }
  if (g == 0){
    size_t base = ((size_t)(kz*32 + bh))*S_ + qbase + lq;   // [kz][bh][2048]
    #pragma unroll
    for (int qs = 0; qs < 4; qs++){
      Zp[base + qs*16] = Z[qs];
      Mp[base + qs*16] = Mm[qs];
    }
  }
}

// ---------------- finalize: s[b,h] = sum_q (Z-M)/Z over kz slots ------
__global__ __launch_bounds__(256) void finalize_s(const float* __restrict__ Zp,
                                                  const float* __restrict__ Mp,
                                                  float* __restrict__ sbh){
  const int bh = blockIdx.x;            // 32 blocks
  const int t = threadIdx.x;
  float acc = 0.f;
  for (int q = t; q < S_; q += 256){
    float z = 0.f, m = 0.f;
    #pragma unroll
    for (int kz = 0; kz < 8; kz++){
      size_t idx = ((size_t)(kz*32 + bh))*S_ + q;
      z += Zp[idx];
      m += Mp[idx];
    }
    acc += (z - m) / z;
  }
  #pragma unroll
  for (int m = 1; m < 64; m <<= 1) acc += __shfl_xor(acc, m);
  __shared__ float wsum[4];
  if ((t & 63) == 0) wsum[t >> 6] = acc;
  __syncthreads();
  if (t == 0) sbh[bh] = wsum[0] + wsum[1] + wsum[2] + wsum[3];
}

// ---------------- fold s into Wo columns: WoST[b][n][k] = WoT[n][k]*s[b,k/64]
__global__ void scale_woT_kernel(const unsigned short* __restrict__ WoT,
                                 const float* __restrict__ sbh,
                                 unsigned short* __restrict__ outw){
  int i = blockIdx.x*256 + threadIdx.x;   // 131072 threads, 8 elems each
  size_t e = (size_t)i * 8;
  int k = (int)(e & 511);
  int n = (int)((e >> 9) & 511);
  int b = (int)(e >> 18);
  float sv = sbh[b*H_ + (k >> 6)];
  short8 wv = *(const short8*)(WoT + (size_t)n*D_ + k);
  short8 o;
  #pragma unroll
  for (int j = 0; j < 8; j++) o[j] = (short)f2bf(bf2f((unsigned short)wv[j]) * sv);
  *(short8*)(outw + e) = o;
}

extern "C" void kernel_launch(void* const* d_in, const int* in_sizes, int n_in,
                              void* d_out, int out_size, void* d_ws, size_t ws_size,
                              hipStream_t stream) {
  (void)in_sizes; (void)n_in; (void)out_size; (void)ws_size;
  const float* x  = (const float*)d_in[0];
  const int* mask = (const int*)d_in[1];
  const float* Wq = (const float*)d_in[2];
  const float* bq = (const float*)d_in[3];
  const float* Wk = (const float*)d_in[4];
  const float* bk = (const float*)d_in[5];
  const float* Wv = (const float*)d_in[6];
  const float* bv = (const float*)d_in[7];
  const float* Wo = (const float*)d_in[8];
  const float* bo = (const float*)d_in[9];
  float* out = (float*)d_out;

  char* ws = (char*)d_ws;
  unsigned short* xb   = (unsigned short*)(ws);             // 8 MB, dead after QKV gemm
  unsigned short* wT   = (unsigned short*)(ws +  8388608);  // WqT,WkT,WvT,WoT (4x512 KB)
  unsigned short* woT  = (unsigned short*)(ws +  9961472);  //   (= wT + 3*262144)
  unsigned short* Qb   = (unsigned short*)(ws + 10485760);
  unsigned short* Kb   = (unsigned short*)(ws + 18874368);
  unsigned short* Vb   = (unsigned short*)(ws + 27262976);
  unsigned short* woST = (unsigned short*)(ws + 35651584);  // 4x512 KB
  float*          sbh  = (float*)         (ws + 37748736);  // 32 floats
  // Z/M per-kz partials overlap the (dead-by-then) xb region: 2 x 2 MB
  float*          Zp   = (float*)(ws);
  float*          Mp   = (float*)(ws + 2097152);
  // mask bit array (2MB) overlaps woST: bits die before scale_woT writes it
  unsigned char*  bits = (unsigned char*)(ws + 35651584);

  prep_kernel<<<5120, 256, 0, stream>>>(x, xb, mask, bits, Wq, Wk, Wv, Wo, wT);

  // QKV projections: z=0..2 -> Q,K,V (bias for Q scaled by SCALE*log2e too)
  gemm_bt<unsigned short><<<dim3(4,64,3), 256, 0, stream>>>(
      xb, 0LL, wT, 262144LL, bq, bk, bv, SCALE_L2E_, 1.0f, 1.0f, Qb, 4194304LL);

  attn_zm_kernel<<<1024, 512, 0, stream>>>(Qb, Kb, (const unsigned*)bits, Zp, Mp);
  finalize_s<<<32, 256, 0, stream>>>(Zp, Mp, sbh);

  scale_woT_kernel<<<512, 256, 0, stream>>>(woT, sbh, woST);

  // out[b] = V[b] @ WoST[b]^T + bo  (fp32 out)
  gemm_bt<float><<<dim3(4,16,4), 256, 0, stream>>>(
      Vb, 1048576LL, woST, 262144LL, bo, bo, bo, 1.0f, 1.0f, 1.0f, out, 1048576LL);
}